// Round 3
// baseline (394.694 us; speedup 1.0000x reference)
//
#include <hip/hip_runtime.h>

// RT-DETRv2 multiscale deformable attention, MI355X/gfx950.
// B=16, Q=300, S=8400 (80x80+40x40+20x20), D=256, H=8, HD=32, L=3, P=4, LP=12.
// Inputs: fp32 (per reference; round-1 NaN / round-2 finite-garbage evidence).
// Output: fp32 (reference output dtype; round-2 absmax 0.1758 matched the
//         "bf16 written into fp32 buffer" signature exactly).
//
//   K1 gemm_nt<bf16 out>:  value = enc @ w_value^T + b -> ws bf16 [b][s][h][32]
//   K2 proj:               logits + softmax + sample locations (fp32) -> ws
//   K3 sample:             bilinear gather + attn-weighted sum -> ws fp32
//   K4 gemm_nt<fp32 out>:  out = sampled @ w_out^T + b_out -> d_out fp32

typedef __attribute__((ext_vector_type(8))) short short8;   // MFMA A/B frag (8 bf16)
typedef __attribute__((ext_vector_type(4))) float f32x4;    // MFMA accumulator

__device__ __forceinline__ unsigned short f2bf(float f) {   // fp32 -> bf16 RTNE
    union { float f; unsigned int i; } v; v.f = f;
    unsigned int r = v.i + 0x7FFFu + ((v.i >> 16) & 1u);
    return (unsigned short)(r >> 16);
}
__device__ __forceinline__ float bf2f(unsigned short u) {
    union { unsigned int i; float f; } v;
    v.i = ((unsigned int)u) << 16;
    return v.f;
}

// C[M x 256] = A[M x 256] @ W[256 x 256]^T + bias.  A,W,bias fp32.
// OUT_BF16: store bf16 (ushort) else fp32.
// 256 thr = 4 waves; block tile 64 rows x 256 cols; wave owns 16 rows.
// W staged in LDS pre-swizzled to B-frag order (one ds_read_b128 per fragment),
// fp32->bf16 RTNE on the way in. A frags straight from global (32B/lane/chunk).
template <bool OUT_BF16>
__global__ __launch_bounds__(256) void gemm_nt(
    const float* __restrict__ A,
    const float* __restrict__ W,
    const float* __restrict__ bias,
    void* __restrict__ Cv)
{
    __shared__ short8 lb[16 * 64];   // 16 KiB
    const int tid  = threadIdx.x;
    const int wave = tid >> 6;
    const int lane = tid & 63;
    const int row0 = blockIdx.x * 64 + wave * 16;

    f32x4 acc[16];
#pragma unroll
    for (int t = 0; t < 16; ++t) acc[t] = (f32x4){0.f, 0.f, 0.f, 0.f};

    const int am = row0 + (lane & 15);   // A row for this lane's fragment
    const int kq = (lane >> 4) << 3;     // k sub-offset within 32-chunk

    for (int kc = 0; kc < 256; kc += 32) {
        __syncthreads();
        // stage B tile: slot (tile,fragLane) = W[n=tile*16+(l&15)][kc+(l>>4)*8 ..+8)
#pragma unroll
        for (int i = 0; i < 4; ++i) {
            int s = tid + (i << 8);
            int n = ((s >> 6) << 4) + (s & 15);
            int k = kc + (((s >> 4) & 3) << 3);
            const float* p = W + n * 256 + k;
            f32x4 x = *(const f32x4*)p;
            f32x4 y = *(const f32x4*)(p + 4);
            short8 r;
#pragma unroll
            for (int q = 0; q < 4; ++q) {
                r[q]     = (short)f2bf(x[q]);
                r[q + 4] = (short)f2bf(y[q]);
            }
            lb[s] = r;
        }
        __syncthreads();

        const float* ap = A + (size_t)am * 256 + kc + kq;
        f32x4 ax = *(const f32x4*)ap;
        f32x4 ay = *(const f32x4*)(ap + 4);
        short8 a;
#pragma unroll
        for (int q = 0; q < 4; ++q) {
            a[q]     = (short)f2bf(ax[q]);
            a[q + 4] = (short)f2bf(ay[q]);
        }
#pragma unroll
        for (int t = 0; t < 16; ++t) {
            short8 b = lb[t * 64 + lane];
            acc[t] = __builtin_amdgcn_mfma_f32_16x16x32_bf16(a, b, acc[t], 0, 0, 0);
        }
    }

    // epilogue: D[row][col], col = lane&15, row = (lane>>4)*4 + reg
    const int ncol = lane & 15;
    const int rb   = row0 + ((lane >> 4) << 2);
#pragma unroll
    for (int t = 0; t < 16; ++t) {
        int n = (t << 4) + ncol;
        float bv = bias[n];
#pragma unroll
        for (int r = 0; r < 4; ++r) {
            float v = acc[t][r] + bv;
            if (OUT_BF16)
                ((unsigned short*)Cv)[(size_t)(rb + r) * 256 + n] = f2bf(v);
            else
                ((float*)Cv)[(size_t)(rb + r) * 256 + n] = v;
        }
    }
}

// 8 (b,q) rows per block. 288 logits/row (192 offsets + 96 attn), fp32 exact.
// attn_out fp32 [rq][h*12+lp]; loc_out fp32 [rq][h*24+lp*2+xy].
__global__ __launch_bounds__(256) void proj_kernel(
    const float* __restrict__ hidden,
    const float* __restrict__ w_off,  const float* __restrict__ b_off,
    const float* __restrict__ w_attn, const float* __restrict__ b_attn,
    const float* __restrict__ refp,
    float* __restrict__ attn_out, float* __restrict__ loc_out)
{
    const int rq0 = blockIdx.x * 8;
    const int tid = threadIdx.x;
    __shared__ float hrow[8][256];
    __shared__ float logits[8][288];

#pragma unroll
    for (int i = 0; i < 8; ++i)
        hrow[i][tid] = hidden[(size_t)(rq0 + i) * 256 + tid];
    __syncthreads();

    for (int pass = 0; pass < 2; ++pass) {
        int j;
        if (pass == 0) j = tid;
        else { if (tid >= 32) break; j = 256 + tid; }
        const float* wrow; float bs;
        if (j < 192) { wrow = w_off  + (size_t)j * 256;         bs = b_off[j]; }
        else         { wrow = w_attn + (size_t)(j - 192) * 256; bs = b_attn[j - 192]; }
        float acc[8];
#pragma unroll
        for (int r = 0; r < 8; ++r) acc[r] = 0.f;
        for (int k = 0; k < 256; k += 4) {
            f32x4 wv = *(const f32x4*)(wrow + k);
#pragma unroll
            for (int r = 0; r < 8; ++r) {
#pragma unroll
                for (int i = 0; i < 4; ++i)
                    acc[r] += hrow[r][k + i] * wv[i];
            }
        }
#pragma unroll
        for (int r = 0; r < 8; ++r) logits[r][j] = acc[r] + bs;
    }
    __syncthreads();

    if (tid < 64) {   // softmax per (row, head) over LP=12
        int r = tid >> 3, h = tid & 7;
        float m = -1e30f;
        for (int p = 0; p < 12; ++p) m = fmaxf(m, logits[r][192 + h * 12 + p]);
        float e[12], sum = 0.f;
        for (int p = 0; p < 12; ++p) { e[p] = __expf(logits[r][192 + h * 12 + p] - m); sum += e[p]; }
        float inv = 1.f / sum;
        for (int p = 0; p < 12; ++p)
            attn_out[(size_t)(rq0 + r) * 96 + h * 12 + p] = e[p] * inv;
    }
    if (tid < 192) {  // loc = ref_xy + logit * (1/P) * 0.5 * ref_wh
        int xy = tid & 1;
#pragma unroll
        for (int r = 0; r < 8; ++r) {
            int rq = rq0 + r;
            float rc  = refp[(size_t)rq * 4 + xy];
            float rwh = refp[(size_t)rq * 4 + 2 + xy];
            loc_out[(size_t)rq * 192 + tid] = rc + logits[r][tid] * 0.125f * rwh;
        }
    }
}

// One block per (b,q). Thread = h*32 + c. 12 points x 4 corners; the 32 channel
// lanes of a head read one contiguous 64B bf16 segment per corner.
__global__ __launch_bounds__(256) void sample_kernel(
    const unsigned short* __restrict__ value,   // bf16 [b][s][h][32]
    const float* __restrict__ attnw, const float* __restrict__ locw,
    float* __restrict__ sampled)
{
    const int rq  = blockIdx.x;
    const int b   = rq / 300;
    const int tid = threadIdx.x;
    const int h   = tid >> 5;
    const int c   = tid & 31;
    const size_t vb = (size_t)b * 8400;

    const int Ws[3] = {80, 40, 20};
    const int Hs[3] = {80, 40, 20};
    const int st[3] = {0, 6400, 8000};

    float acc = 0.f;
#pragma unroll
    for (int l = 0; l < 3; ++l) {
        const int Wl = Ws[l], Hl = Hs[l], s0 = st[l];
#pragma unroll
        for (int p = 0; p < 4; ++p) {
            const int lp = l * 4 + p;
            float lx = locw[(size_t)rq * 192 + h * 24 + lp * 2];
            float ly = locw[(size_t)rq * 192 + h * 24 + lp * 2 + 1];
            float aw = attnw[(size_t)rq * 96 + h * 12 + lp];
            float gx = lx * (float)Wl - 0.5f;
            float gy = ly * (float)Hl - 0.5f;
            float x0f = floorf(gx), y0f = floorf(gy);
            int   x0  = (int)x0f,  y0  = (int)y0f;
            float wx1 = gx - x0f, wx0 = 1.f - wx1;
            float wy1 = gy - y0f, wy0 = 1.f - wy1;
#pragma unroll
            for (int dy = 0; dy < 2; ++dy) {
                int y = y0 + dy;
                if (y < 0 || y >= Hl) continue;
                float wy = dy ? wy1 : wy0;
#pragma unroll
                for (int dx = 0; dx < 2; ++dx) {
                    int x = x0 + dx;
                    if (x < 0 || x >= Wl) continue;
                    float wx = dx ? wx1 : wx0;
                    float v = bf2f(value[((vb + (size_t)(s0 + y * Wl + x)) * 8 + h) * 32 + c]);
                    acc += aw * wy * wx * v;
                }
            }
        }
    }
    sampled[(size_t)rq * 256 + tid] = acc;
}

extern "C" void kernel_launch(void* const* d_in, const int* in_sizes, int n_in,
                              void* d_out, int out_size, void* d_ws, size_t ws_size,
                              hipStream_t stream)
{
    const float* hidden  = (const float*)d_in[0];
    const float* enc     = (const float*)d_in[1];
    const float* refp    = (const float*)d_in[2];
    const float* w_value = (const float*)d_in[3];
    const float* b_value = (const float*)d_in[4];
    const float* w_off   = (const float*)d_in[5];
    const float* b_off   = (const float*)d_in[6];
    const float* w_attn  = (const float*)d_in[7];
    const float* b_attn  = (const float*)d_in[8];
    const float* w_out   = (const float*)d_in[9];
    const float* b_out   = (const float*)d_in[10];

    // ws layout (16B aligned):
    //   value   bf16 [16][8400][8][32] = 68,812,800 B
    //   sampled fp32 [4800][256]       =  4,915,200 B
    //   attnw   fp32 [4800][96]        =  1,843,200 B
    //   locw    fp32 [4800][192]       =  3,686,400 B   (total 79,257,600 B)
    char* ws = (char*)d_ws;
    unsigned short* value   = (unsigned short*)ws;
    float*          sampled = (float*)(ws + 68812800);
    float*          attnw   = (float*)(ws + 68812800 + 4915200);
    float*          locw    = (float*)(ws + 68812800 + 4915200 + 1843200);

    gemm_nt<true><<<2100, 256, 0, stream>>>(enc, w_value, b_value, value);   // K1
    proj_kernel<<<600, 256, 0, stream>>>(hidden, w_off, b_off, w_attn,       // K2
                                         b_attn, refp, attnw, locw);
    sample_kernel<<<4800, 256, 0, stream>>>(value, attnw, locw, sampled);    // K3
    gemm_nt<false><<<75, 256, 0, stream>>>(sampled, w_out, b_out, d_out);    // K4
}

// Round 4
// 329.355 us; speedup vs baseline: 1.1984x; 1.1984x over previous
//
#include <hip/hip_runtime.h>

// RT-DETRv2 multiscale deformable attention, MI355X/gfx950.
// B=16, Q=300, S=8400 (80x80+40x40+20x20), D=256, H=8, HD=32, L=3, P=4, LP=12.
// Inputs fp32, output fp32 (verified round 3: absmax 5.2e-4).
//
//   K0 prep:      pre-swizzle weights fp32->bf16 into LDS-staging order
//   K1 gemm_nt:   value = enc @ w_value^T + b      -> ws bf16 [b][s][h][32]
//   K2 proj_gemm: MFMA logits + fused softmax/loc  -> ws attnw/locw fp32
//   K3 sample:    bilinear gather + weighted sum   -> ws sampled bf16
//   K4 gemm_nt:   out = sampled @ w_out^T + b_out  -> d_out fp32

typedef __attribute__((ext_vector_type(8))) short short8;   // MFMA A/B frag (8 bf16)
typedef __attribute__((ext_vector_type(4))) float f32x4;    // MFMA accumulator

__device__ __forceinline__ unsigned short f2bf(float f) {   // fp32 -> bf16 RTNE
    union { float f; unsigned int i; } v; v.f = f;
    unsigned int r = v.i + 0x7FFFu + ((v.i >> 16) & 1u);
    return (unsigned short)(r >> 16);
}
__device__ __forceinline__ float bf2f(unsigned short u) {
    union { unsigned int i; float f; } v;
    v.i = ((unsigned int)u) << 16;
    return v.f;
}
__device__ __forceinline__ short8 cvt8(const float* p) {
    f32x4 x = *(const f32x4*)p;
    f32x4 y = *(const f32x4*)(p + 4);
    short8 r;
#pragma unroll
    for (int q = 0; q < 4; ++q) {
        r[q]     = (short)f2bf(x[q]);
        r[q + 4] = (short)f2bf(y[q]);
    }
    return r;
}

// ---- K0: pre-swizzle weights into B-fragment staging order (bf16) ----------
// Slot layout (per 256x256 W, 16 n-tiles): s = kcb*1024 + tile*64 + fragLane;
// holds W[n = tile*16 + (fl&15)][kcb*32 + (fl>>4)*8 .. +8).  Proj W has 18
// n-tiles (288 rows = w_off ++ w_attn), 1152 slots per kcb.
__global__ __launch_bounds__(256) void prep_kernel(
    const float* __restrict__ wv, const float* __restrict__ wo,
    const float* __restrict__ w_off, const float* __restrict__ w_attn,
    short8* __restrict__ wv_s, short8* __restrict__ wo_s, short8* __restrict__ wp_s)
{
    const int blk = blockIdx.x, tid = threadIdx.x;
    if (blk < 64) {
        const float* W = (blk < 32) ? wv : wo;
        short8* out    = (blk < 32) ? wv_s : wo_s;
        int s   = ((blk & 31) << 8) + tid;           // 0..8191
        int kcb = s >> 10, sl = s & 1023;
        int n = ((sl >> 6) << 4) + (sl & 15);
        int k = (kcb << 5) + (((sl >> 4) & 3) << 3);
        out[s] = cvt8(W + n * 256 + k);
    } else {
        int s   = ((blk - 64) << 8) + tid;           // 0..9215
        int kcb = s / 1152, sl = s - kcb * 1152;
        int n = ((sl >> 6) << 4) + (sl & 15);        // 0..287
        int k = (kcb << 5) + (((sl >> 4) & 3) << 3);
        const float* p = (n < 192) ? (w_off + (size_t)n * 256 + k)
                                   : (w_attn + (size_t)(n - 192) * 256 + k);
        wp_s[s] = cvt8(p);
    }
}

// ---- K1/K4: C[M x 256] = A[M x 256] @ W^T + bias ---------------------------
// A fp32 or bf16 (A_BF16); C bf16 or fp32 (OUT_BF16). W pre-swizzled bf16.
// 256 thr = 4 waves; block tile 64 rows x 256 cols; wave owns 16 rows.
template <bool A_BF16, bool OUT_BF16>
__global__ __launch_bounds__(256) void gemm_nt(
    const void* __restrict__ Av,
    const short8* __restrict__ Wswz,
    const float* __restrict__ bias,
    void* __restrict__ Cv)
{
    __shared__ short8 lb[1024];   // 16 KiB
    const int tid  = threadIdx.x;
    const int wave = tid >> 6;
    const int lane = tid & 63;
    const int row0 = blockIdx.x * 64 + wave * 16;

    f32x4 acc[16];
#pragma unroll
    for (int t = 0; t < 16; ++t) acc[t] = (f32x4){0.f, 0.f, 0.f, 0.f};

    const int am = row0 + (lane & 15);   // A row for this lane's fragment
    const int kq = (lane >> 4) << 3;     // k sub-offset within 32-chunk

    for (int kcb = 0; kcb < 8; ++kcb) {
        __syncthreads();
#pragma unroll
        for (int i = 0; i < 4; ++i) {
            int s = tid + (i << 8);
            lb[s] = Wswz[(kcb << 10) + s];   // 16B L2-hot copy, no converts
        }
        __syncthreads();

        short8 a;
        if (A_BF16) {
            a = *(const short8*)((const unsigned short*)Av + (size_t)am * 256 + (kcb << 5) + kq);
        } else {
            a = cvt8((const float*)Av + (size_t)am * 256 + (kcb << 5) + kq);
        }
#pragma unroll
        for (int t = 0; t < 16; ++t)
            acc[t] = __builtin_amdgcn_mfma_f32_16x16x32_bf16(a, lb[t * 64 + lane], acc[t], 0, 0, 0);
    }

    // epilogue: D[row][col], col = lane&15, row = (lane>>4)*4 + reg
    const int ncol = lane & 15;
    const int rb   = row0 + ((lane >> 4) << 2);
#pragma unroll
    for (int t = 0; t < 16; ++t) {
        int n = (t << 4) + ncol;
        float bv = bias[n];
#pragma unroll
        for (int r = 0; r < 4; ++r) {
            float v = acc[t][r] + bv;
            if (OUT_BF16)
                ((unsigned short*)Cv)[(size_t)(rb + r) * 256 + n] = f2bf(v);
            else
                ((float*)Cv)[(size_t)(rb + r) * 256 + n] = v;
        }
    }
}

// ---- K2: proj logits (MFMA) + fused softmax + sample locations -------------
// Block tile: 32 query-rows x 288 cols. 4 waves: wave = rowgroup(2) x colhalf(2),
// each wave 16 rows x 9 n-tiles. Logits land in LDS, epilogue does softmax
// (per row,head over LP=12) and loc = ref_xy + logit*0.125*ref_wh.
#define LGS 296   // padded LDS stride (floats) to break 288%32==0 bank pattern
__global__ __launch_bounds__(256) void proj_gemm(
    const float* __restrict__ hidden,
    const short8* __restrict__ Wswz,
    const float* __restrict__ b_off, const float* __restrict__ b_attn,
    const float* __restrict__ refp,
    float* __restrict__ attnw, float* __restrict__ locw)
{
    __shared__ char smem[32 * LGS * 4];               // 37,888 B (>= 1152*16 staging)
    short8* lb = (short8*)smem;                       // [1152] during K-loop
    float*  lg = (float*)smem;                        // [32][LGS] after

    const int tid  = threadIdx.x;
    const int wave = tid >> 6;
    const int lane = tid & 63;
    const int rq0  = blockIdx.x * 32;
    const int rg   = wave >> 1;          // row group 0/1
    const int ts   = (wave & 1) * 9;     // n-tile start 0/9
    const int row0 = rq0 + rg * 16;

    f32x4 acc[9];
#pragma unroll
    for (int t = 0; t < 9; ++t) acc[t] = (f32x4){0.f, 0.f, 0.f, 0.f};

    const int am = row0 + (lane & 15);
    const int kq = (lane >> 4) << 3;

    for (int kcb = 0; kcb < 8; ++kcb) {
        __syncthreads();
#pragma unroll
        for (int i = 0; i < 5; ++i) {
            int s = tid + (i << 8);
            if (s < 1152) lb[s] = Wswz[kcb * 1152 + s];
        }
        __syncthreads();

        short8 a = cvt8(hidden + (size_t)am * 256 + (kcb << 5) + kq);
#pragma unroll
        for (int t = 0; t < 9; ++t)
            acc[t] = __builtin_amdgcn_mfma_f32_16x16x32_bf16(a, lb[(ts + t) * 64 + lane], acc[t], 0, 0, 0);
    }

    __syncthreads();   // staging dead; reuse smem as logits
    const int ncol = lane & 15;
    const int rb   = rg * 16 + ((lane >> 4) << 2);    // row within block tile
#pragma unroll
    for (int t = 0; t < 9; ++t) {
        int n = (ts + t) * 16 + ncol;
        float bv = (n < 192) ? b_off[n] : b_attn[n - 192];
#pragma unroll
        for (int r = 0; r < 4; ++r)
            lg[(rb + r) * LGS + n] = acc[t][r] + bv;
    }
    __syncthreads();

    {   // softmax: 256 tasks = 32 rows x 8 heads, one per thread
        int r = tid >> 3, h = tid & 7;
        const float* lrow = lg + r * LGS + 192 + h * 12;
        float m = -1e30f;
#pragma unroll
        for (int p = 0; p < 12; ++p) m = fmaxf(m, lrow[p]);
        float e[12], sum = 0.f;
#pragma unroll
        for (int p = 0; p < 12; ++p) { e[p] = __expf(lrow[p] - m); sum += e[p]; }
        float inv = 1.f / sum;
        float* ao = attnw + (size_t)(rq0 + r) * 96 + h * 12;
#pragma unroll
        for (int p = 0; p < 12; ++p) ao[p] = e[p] * inv;
    }
    if (tid < 192) {   // loc: 192 offset logits x 32 rows
        int xy = tid & 1;
        for (int r = 0; r < 32; ++r) {
            int rq = rq0 + r;
            float rc  = refp[(size_t)rq * 4 + xy];
            float rwh = refp[(size_t)rq * 4 + 2 + xy];
            locw[(size_t)rq * 192 + tid] = rc + lg[r * LGS + tid] * 0.125f * rwh;
        }
    }
}

// ---- K3: deformable bilinear sampling --------------------------------------
// One block per (b,q). Thread = h*32 + c. loc/attn staged in LDS.
__global__ __launch_bounds__(256) void sample_kernel(
    const unsigned short* __restrict__ value,   // bf16 [b][s][h][32]
    const float* __restrict__ attnw, const float* __restrict__ locw,
    unsigned short* __restrict__ sampled)       // bf16 [rq][256]
{
    const int rq  = blockIdx.x;
    const int b   = rq / 300;
    const int tid = threadIdx.x;
    const int h   = tid >> 5;
    const int c   = tid & 31;
    const size_t vb = (size_t)b * 8400;

    __shared__ float sm[288];   // [0,192) loc, [192,288) attn
    {
        int j = tid;
        sm[j] = (j < 192) ? locw[(size_t)rq * 192 + j]
                          : attnw[(size_t)rq * 96 + (j - 192)];
        if (tid < 32) sm[256 + tid] = attnw[(size_t)rq * 96 + 64 + tid];
    }
    __syncthreads();

    const int Ws[3] = {80, 40, 20};
    const int Hs[3] = {80, 40, 20};
    const int st[3] = {0, 6400, 8000};

    float acc = 0.f;
#pragma unroll
    for (int l = 0; l < 3; ++l) {
        const int Wl = Ws[l], Hl = Hs[l], s0 = st[l];
#pragma unroll
        for (int p = 0; p < 4; ++p) {
            const int lp = l * 4 + p;
            float lx = sm[h * 24 + lp * 2];
            float ly = sm[h * 24 + lp * 2 + 1];
            float aw = sm[192 + h * 12 + lp];
            float gx = lx * (float)Wl - 0.5f;
            float gy = ly * (float)Hl - 0.5f;
            float x0f = floorf(gx), y0f = floorf(gy);
            int   x0  = (int)x0f,  y0  = (int)y0f;
            float wx1 = gx - x0f, wx0 = 1.f - wx1;
            float wy1 = gy - y0f, wy0 = 1.f - wy1;
#pragma unroll
            for (int dy = 0; dy < 2; ++dy) {
                int y = y0 + dy;
                if (y < 0 || y >= Hl) continue;
                float wy = dy ? wy1 : wy0;
#pragma unroll
                for (int dx = 0; dx < 2; ++dx) {
                    int x = x0 + dx;
                    if (x < 0 || x >= Wl) continue;
                    float wx = dx ? wx1 : wx0;
                    float v = bf2f(value[((vb + (size_t)(s0 + y * Wl + x)) * 8 + h) * 32 + c]);
                    acc += aw * wy * wx * v;
                }
            }
        }
    }
    sampled[(size_t)rq * 256 + tid] = f2bf(acc);
}

extern "C" void kernel_launch(void* const* d_in, const int* in_sizes, int n_in,
                              void* d_out, int out_size, void* d_ws, size_t ws_size,
                              hipStream_t stream)
{
    const float* hidden  = (const float*)d_in[0];
    const float* enc     = (const float*)d_in[1];
    const float* refp    = (const float*)d_in[2];
    const float* w_value = (const float*)d_in[3];
    const float* b_value = (const float*)d_in[4];
    const float* w_off   = (const float*)d_in[5];
    const float* b_off   = (const float*)d_in[6];
    const float* w_attn  = (const float*)d_in[7];
    const float* b_attn  = (const float*)d_in[8];
    const float* w_out   = (const float*)d_in[9];
    const float* b_out   = (const float*)d_in[10];

    // ws layout (16B aligned), total 77,209,600 B (round 3 proved >= 79,257,600 ok):
    //   value   bf16 [16][8400][8][32] = 68,812,800
    //   sampled bf16 [4800][256]       =  2,457,600
    //   attnw   fp32 [4800][96]        =  1,843,200
    //   locw    fp32 [4800][192]       =  3,686,400
    //   wv_swz  short8[8192]           =    131,072
    //   wo_swz  short8[8192]           =    131,072
    //   wp_swz  short8[9216]           =    147,456
    char* ws = (char*)d_ws;
    unsigned short* value   = (unsigned short*)ws;
    unsigned short* sampled = (unsigned short*)(ws + 68812800);
    float*          attnw   = (float*)(ws + 71270400);
    float*          locw    = (float*)(ws + 73113600);
    short8*         wv_swz  = (short8*)(ws + 76800000);
    short8*         wo_swz  = (short8*)(ws + 76931072);
    short8*         wp_swz  = (short8*)(ws + 77062144);

    prep_kernel<<<100, 256, 0, stream>>>(w_value, w_out, w_off, w_attn,       // K0
                                         wv_swz, wo_swz, wp_swz);
    gemm_nt<false, true><<<2100, 256, 0, stream>>>(enc, wv_swz, b_value,      // K1
                                                   value);
    proj_gemm<<<150, 256, 0, stream>>>(hidden, wp_swz, b_off, b_attn,         // K2
                                       refp, attnw, locw);
    sample_kernel<<<4800, 256, 0, stream>>>(value, attnw, locw, sampled);     // K3
    gemm_nt<true, false><<<75, 256, 0, stream>>>(sampled, wo_swz, b_out,      // K4
                                                 d_out);
}

// Round 5
// 314.854 us; speedup vs baseline: 1.2536x; 1.0461x over previous
//
#include <hip/hip_runtime.h>

// RT-DETRv2 multiscale deformable attention, MI355X/gfx950.
// B=16, Q=300, S=8400 (80x80+40x40+20x20), D=256, H=8, HD=32, L=3, P=4, LP=12.
// Inputs fp32, output fp32 (verified round 3/4; absmax 1.2e-3 vs thr 2.7e-3).
//
//   K0 prep:      pre-swizzle weights fp32->bf16 into LDS-staging order
//   K1 gemm_nt<2>: value = enc @ w_value^T + b     -> ws bf16 [b][s][h][32]
//   K2 proj_gemm: MFMA logits + fused softmax/loc  -> ws attnw/locw fp32
//   K3 sample:    precomputed-corner gather + sum  -> ws sampled bf16
//   K4 gemm_nt<1>: out = sampled @ w_out^T + b_out -> d_out fp32

typedef __attribute__((ext_vector_type(8))) short short8;   // MFMA A/B frag (8 bf16)
typedef __attribute__((ext_vector_type(4))) float f32x4;    // MFMA accumulator

__device__ __forceinline__ unsigned short f2bf(float f) {   // fp32 -> bf16 RTNE
    union { float f; unsigned int i; } v; v.f = f;
    unsigned int r = v.i + 0x7FFFu + ((v.i >> 16) & 1u);
    return (unsigned short)(r >> 16);
}
__device__ __forceinline__ float bf2f(unsigned short u) {
    union { unsigned int i; float f; } v;
    v.i = ((unsigned int)u) << 16;
    return v.f;
}
__device__ __forceinline__ short8 cvt8(const float* p) {
    f32x4 x = *(const f32x4*)p;
    f32x4 y = *(const f32x4*)(p + 4);
    short8 r;
#pragma unroll
    for (int q = 0; q < 4; ++q) {
        r[q]     = (short)f2bf(x[q]);
        r[q + 4] = (short)f2bf(y[q]);
    }
    return r;
}
// async global->LDS 16B (CK-style addrspace cast via uintptr round-trip:
// LDS generic addr low 32 bits are the LDS offset)
__device__ __forceinline__ void gl_lds16(const short8* g, short8* l) {
    __builtin_amdgcn_global_load_lds(
        (const __attribute__((address_space(1))) void*)(unsigned long long)(const void*)g,
        (__attribute__((address_space(3))) void*)(unsigned int)(unsigned long long)(void*)l,
        16, 0, 0);
}

// ---- K0: pre-swizzle weights into B-fragment staging order (bf16) ----------
// Slot s = kcb*1024 + tile*64 + fragLane holds
// W[n = tile*16 + (fl&15)][kcb*32 + (fl>>4)*8 .. +8).  Proj W: 18 n-tiles
// (288 rows = w_off ++ w_attn), 1152 slots/kcb.
__global__ __launch_bounds__(256) void prep_kernel(
    const float* __restrict__ wv, const float* __restrict__ wo,
    const float* __restrict__ w_off, const float* __restrict__ w_attn,
    short8* __restrict__ wv_s, short8* __restrict__ wo_s, short8* __restrict__ wp_s)
{
    const int blk = blockIdx.x, tid = threadIdx.x;
    if (blk < 64) {
        const float* W = (blk < 32) ? wv : wo;
        short8* out    = (blk < 32) ? wv_s : wo_s;
        int s   = ((blk & 31) << 8) + tid;
        int kcb = s >> 10, sl = s & 1023;
        int n = ((sl >> 6) << 4) + (sl & 15);
        int k = (kcb << 5) + (((sl >> 4) & 3) << 3);
        out[s] = cvt8(W + n * 256 + k);
    } else {
        int s   = ((blk - 64) << 8) + tid;
        int kcb = s / 1152, sl = s - kcb * 1152;
        int n = ((sl >> 6) << 4) + (sl & 15);
        int k = (kcb << 5) + (((sl >> 4) & 3) << 3);
        const float* p = (n < 192) ? (w_off + (size_t)n * 256 + k)
                                   : (w_attn + (size_t)(n - 192) * 256 + k);
        wp_s[s] = cvt8(p);
    }
}

// ---- K1/K4: C[M x 256] = A[M x 256] @ W^T + bias ---------------------------
// RPW row-fragments per wave (B-fragment reuse: 16 ds_read vs 16*RPW MFMA).
// Block = 4 waves, tile 64*RPW rows x 256 cols. W staged via global_load_lds.
template <int RPW, bool A_BF16, bool OUT_BF16>
__global__ __launch_bounds__(256) void gemm_nt(
    const void* __restrict__ Av,
    const short8* __restrict__ Wswz,
    const float* __restrict__ bias,
    void* __restrict__ Cv)
{
    __shared__ short8 lb[1024];   // 16 KiB
    const int tid  = threadIdx.x;
    const int wave = tid >> 6;
    const int lane = tid & 63;
    const int row0 = blockIdx.x * (64 * RPW) + wave * (16 * RPW);

    f32x4 acc[RPW][16];
#pragma unroll
    for (int r = 0; r < RPW; ++r)
#pragma unroll
        for (int t = 0; t < 16; ++t) acc[r][t] = (f32x4){0.f, 0.f, 0.f, 0.f};

    const int am = row0 + (lane & 15);   // first A row for this lane
    const int kq = (lane >> 4) << 3;     // k sub-offset within 32-chunk

    for (int kcb = 0; kcb < 8; ++kcb) {
        __syncthreads();   // prior ds_reads done before LDS overwrite
#pragma unroll
        for (int i = 0; i < 4; ++i) {
            int s = tid + (i << 8);
            gl_lds16(&Wswz[(kcb << 10) + s], &lb[s]);   // dst = wave base + lane*16
        }
        short8 a[RPW];
#pragma unroll
        for (int r = 0; r < RPW; ++r) {
            if (A_BF16)
                a[r] = *(const short8*)((const unsigned short*)Av
                        + (size_t)(am + 16 * r) * 256 + (kcb << 5) + kq);
            else
                a[r] = cvt8((const float*)Av + (size_t)(am + 16 * r) * 256 + (kcb << 5) + kq);
        }
        __syncthreads();   // drains global_load_lds (vmcnt 0) + publishes LDS

#pragma unroll
        for (int t = 0; t < 16; ++t) {
            short8 b = lb[t * 64 + lane];
#pragma unroll
            for (int r = 0; r < RPW; ++r)
                acc[r][t] = __builtin_amdgcn_mfma_f32_16x16x32_bf16(a[r], b, acc[r][t], 0, 0, 0);
        }
    }

    // epilogue: D[row][col], col = lane&15, row = rowgroup + (lane>>4)*4 + reg
    const int ncol = lane & 15;
#pragma unroll
    for (int r = 0; r < RPW; ++r) {
        const int rb = row0 + r * 16 + ((lane >> 4) << 2);
#pragma unroll
        for (int t = 0; t < 16; ++t) {
            int n = (t << 4) + ncol;
            float bv = bias[n];
#pragma unroll
            for (int rr = 0; rr < 4; ++rr) {
                float v = acc[r][t][rr] + bv;
                if (OUT_BF16)
                    ((unsigned short*)Cv)[(size_t)(rb + rr) * 256 + n] = f2bf(v);
                else
                    ((float*)Cv)[(size_t)(rb + rr) * 256 + n] = v;
            }
        }
    }
}

// ---- K2: proj logits (MFMA) + fused softmax + sample locations -------------
#define LGS 296   // padded LDS row stride (floats)
__global__ __launch_bounds__(256) void proj_gemm(
    const float* __restrict__ hidden,
    const short8* __restrict__ Wswz,
    const float* __restrict__ b_off, const float* __restrict__ b_attn,
    const float* __restrict__ refp,
    float* __restrict__ attnw, float* __restrict__ locw)
{
    __shared__ char smem[32 * LGS * 4];               // >= 1152*16 staging
    short8* lb = (short8*)smem;
    float*  lg = (float*)smem;

    const int tid  = threadIdx.x;
    const int wave = tid >> 6;
    const int lane = tid & 63;
    const int rq0  = blockIdx.x * 32;
    const int rg   = wave >> 1;
    const int ts   = (wave & 1) * 9;
    const int row0 = rq0 + rg * 16;

    f32x4 acc[9];
#pragma unroll
    for (int t = 0; t < 9; ++t) acc[t] = (f32x4){0.f, 0.f, 0.f, 0.f};

    const int am = row0 + (lane & 15);
    const int kq = (lane >> 4) << 3;

    for (int kcb = 0; kcb < 8; ++kcb) {
        __syncthreads();
#pragma unroll
        for (int i = 0; i < 5; ++i) {
            int s = tid + (i << 8);
            if (s < 1152) lb[s] = Wswz[kcb * 1152 + s];
        }
        __syncthreads();

        short8 a = cvt8(hidden + (size_t)am * 256 + (kcb << 5) + kq);
#pragma unroll
        for (int t = 0; t < 9; ++t)
            acc[t] = __builtin_amdgcn_mfma_f32_16x16x32_bf16(a, lb[(ts + t) * 64 + lane], acc[t], 0, 0, 0);
    }

    __syncthreads();
    const int ncol = lane & 15;
    const int rb   = rg * 16 + ((lane >> 4) << 2);
#pragma unroll
    for (int t = 0; t < 9; ++t) {
        int n = (ts + t) * 16 + ncol;
        float bv = (n < 192) ? b_off[n] : b_attn[n - 192];
#pragma unroll
        for (int r = 0; r < 4; ++r)
            lg[(rb + r) * LGS + n] = acc[t][r] + bv;
    }
    __syncthreads();

    {   // softmax: 32 rows x 8 heads, one per thread
        int r = tid >> 3, h = tid & 7;
        const float* lrow = lg + r * LGS + 192 + h * 12;
        float m = -1e30f;
#pragma unroll
        for (int p = 0; p < 12; ++p) m = fmaxf(m, lrow[p]);
        float e[12], sum = 0.f;
#pragma unroll
        for (int p = 0; p < 12; ++p) { e[p] = __expf(lrow[p] - m); sum += e[p]; }
        float inv = 1.f / sum;
        float* ao = attnw + (size_t)(rq0 + r) * 96 + h * 12;
#pragma unroll
        for (int p = 0; p < 12; ++p) ao[p] = e[p] * inv;
    }
    if (tid < 192) {   // loc = ref_xy + logit*0.125*ref_wh
        int xy = tid & 1;
        for (int r = 0; r < 32; ++r) {
            int rq = rq0 + r;
            float rc  = refp[(size_t)rq * 4 + xy];
            float rwh = refp[(size_t)rq * 4 + 2 + xy];
            locw[(size_t)rq * 192 + tid] = rc + lg[r * LGS + tid] * 0.125f * rwh;
        }
    }
}

// ---- K3: deformable bilinear sampling --------------------------------------
// Phase 1 (96 threads): per (h,point) compute 4 clamped corner offsets +
// combined weights aw*wy*wx*valid -> LDS.  Phase 2: pure gather+fma, 48
// independent loads/thread; offsets broadcast from LDS (same addr per half-wave).
__global__ __launch_bounds__(256) void sample_kernel(
    const unsigned short* __restrict__ value,   // bf16 [b][s][h][32]
    const float* __restrict__ attnw, const float* __restrict__ locw,
    unsigned short* __restrict__ sampled)       // bf16 [rq][256]
{
    const int rq  = blockIdx.x;
    const int b   = rq / 300;
    const int tid = threadIdx.x;

    __shared__ int4   soff[96];
    __shared__ float4 swt[96];

    if (tid < 96) {
        int h = tid / 12, lp = tid - h * 12;
        int l = lp >> 2;
        int Wl = (l == 0) ? 80 : (l == 1) ? 40 : 20;        // H == W per level
        int s0 = (l == 0) ? 0  : (l == 1) ? 6400 : 8000;
        float lx = locw[(size_t)rq * 192 + h * 24 + lp * 2];
        float ly = locw[(size_t)rq * 192 + h * 24 + lp * 2 + 1];
        float aw = attnw[(size_t)rq * 96 + h * 12 + lp];
        float gx = lx * (float)Wl - 0.5f;
        float gy = ly * (float)Wl - 0.5f;
        float x0f = floorf(gx), y0f = floorf(gy);
        int   x0 = (int)x0f,   y0 = (int)y0f;
        float wx1 = gx - x0f, wx0 = 1.f - wx1;
        float wy1 = gy - y0f, wy0 = 1.f - wy1;
        int4 of; float4 wt;
#pragma unroll
        for (int j = 0; j < 4; ++j) {
            int x = x0 + (j & 1), y = y0 + (j >> 1);
            bool ok = (x >= 0) & (x < Wl) & (y >= 0) & (y < Wl);
            int idx = ok ? (((b * 8400 + s0 + y * Wl + x) * 8 + h) * 32) : 0;
            float w = ok ? aw * ((j & 1) ? wx1 : wx0) * ((j >> 1) ? wy1 : wy0) : 0.f;
            ((int*)&of)[j] = idx;
            ((float*)&wt)[j] = w;
        }
        soff[tid] = of;
        swt[tid]  = wt;
    }
    __syncthreads();

    const int h = tid >> 5, c = tid & 31;
    float acc = 0.f;
#pragma unroll
    for (int lp = 0; lp < 12; ++lp) {
        int idx = h * 12 + lp;
        int4   of = soff[idx];
        float4 wt = swt[idx];
        acc += wt.x * bf2f(value[of.x + c]);
        acc += wt.y * bf2f(value[of.y + c]);
        acc += wt.z * bf2f(value[of.z + c]);
        acc += wt.w * bf2f(value[of.w + c]);
    }
    sampled[(size_t)rq * 256 + tid] = f2bf(acc);
}

extern "C" void kernel_launch(void* const* d_in, const int* in_sizes, int n_in,
                              void* d_out, int out_size, void* d_ws, size_t ws_size,
                              hipStream_t stream)
{
    const float* hidden  = (const float*)d_in[0];
    const float* enc     = (const float*)d_in[1];
    const float* refp    = (const float*)d_in[2];
    const float* w_value = (const float*)d_in[3];
    const float* b_value = (const float*)d_in[4];
    const float* w_off   = (const float*)d_in[5];
    const float* b_off   = (const float*)d_in[6];
    const float* w_attn  = (const float*)d_in[7];
    const float* b_attn  = (const float*)d_in[8];
    const float* w_out   = (const float*)d_in[9];
    const float* b_out   = (const float*)d_in[10];

    // ws layout: value 68,812,800 | sampled 2,457,600 | attnw 1,843,200 |
    // locw 3,686,400 | wv_swz 131,072 | wo_swz 131,072 | wp_swz 147,456
    char* ws = (char*)d_ws;
    unsigned short* value   = (unsigned short*)ws;
    unsigned short* sampled = (unsigned short*)(ws + 68812800);
    float*          attnw   = (float*)(ws + 71270400);
    float*          locw    = (float*)(ws + 73113600);
    short8*         wv_swz  = (short8*)(ws + 76800000);
    short8*         wo_swz  = (short8*)(ws + 76931072);
    short8*         wp_swz  = (short8*)(ws + 77062144);

    prep_kernel<<<100, 256, 0, stream>>>(w_value, w_out, w_off, w_attn,        // K0
                                         wv_swz, wo_swz, wp_swz);
    gemm_nt<2, false, true><<<1050, 256, 0, stream>>>(enc, wv_swz, b_value,    // K1
                                                      value);
    proj_gemm<<<150, 256, 0, stream>>>(hidden, wp_swz, b_off, b_attn,          // K2
                                       refp, attnw, locw);
    sample_kernel<<<4800, 256, 0, stream>>>(value, attnw, locw, sampled);      // K3
    gemm_nt<1, true, false><<<75, 256, 0, stream>>>(sampled, wo_swz, b_out,    // K4
                                                    d_out);
}